// Round 6
// baseline (141.392 us; speedup 1.0000x reference)
//
#include <hip/hip_runtime.h>
#include <math.h>

#ifndef M_PI
#define M_PI 3.14159265358979323846
#endif

namespace {
constexpr int B_ = 4;
constexpr int L_ = 2048;
constexpr int D_ = 64;
constexpr int H_ = 4;
constexpr int RB = 16;          // rows per block (phase 2)
constexpr int NTILE = 32;       // 64-k tiles
constexpr int CAPC = 256;       // per-wave candidate capacity (thresh)
constexpr int OUTW = D_ + H_ * D_;  // 320
}

typedef __attribute__((ext_vector_type(8))) short bf16x8;
typedef __attribute__((ext_vector_type(4))) float f32x4;

__device__ __forceinline__ unsigned bf16_rne(float x) {
    unsigned u = __float_as_uint(x);
    return (u + 0x7fffu + ((u >> 16) & 1u)) >> 16;
}

// packed f32->bf16 RNE convert (gfx950 HW op)
__device__ __forceinline__ unsigned cvt_pk_bf16(float lo, float hi) {
    unsigned r;
    asm("v_cvt_pk_bf16_f32 %0, %1, %2" : "=v"(r) : "v"(lo), "v"(hi));
    return r;
}

#if defined(__has_builtin)
#if __has_builtin(__builtin_amdgcn_exp2f)
#define EXP2F(x) __builtin_amdgcn_exp2f(x)
#endif
#endif
#ifndef EXP2F
#define EXP2F(x) __expf((x) * 0.69314718055994531f)
#endif

// wait lgkmcnt(0) only (vmcnt=63, expcnt=7)
#define LDS_FENCE() __builtin_amdgcn_s_waitcnt(0xC07F)

// ---- fused prep + per-row threshold kernel (R3-verified verbatim).
__global__ __launch_bounds__(256) void prep_thresh_kernel(
    const float* __restrict__ mesh,
    const float* __restrict__ inputs,
    char* __restrict__ ws,
    float* __restrict__ out)
{
    __shared__ unsigned s_hist[4][256];   // 4 KB (per-wave hist / c2)
    __shared__ float s_cand[4][256];      // 4 KB (per-wave candidates)

    const int t = threadIdx.x;
    const int l = t & 63;
    const int w = t >> 6;                 // 0..3
    const int blk = blockIdx.x;           // 2048

    // ---- prep part: one packed-uint conversion per thread (t<128)
    if (t < 128) {
        const unsigned u = (unsigned)blk * 128u + (unsigned)t;   // < 262144
        const int pb = u >> 16;             // batch
        const int rem = u & 65535;
        const int tile = rem >> 12;         // tile of 128 k
        const int idx = rem & 4095;
        const int n = idx & 63;
        const int kl = (idx >> 6) << 1;     // even k within tile128
        const float* inb = inputs + ((size_t)pb * L_ + tile * 128) * D_;
        char* wsb = ws + (size_t)pb * (L_ * D_ * 2) + tile * (128 * D_ * 2);
        const float x0 = inb[kl * D_ + n];
        const float x1 = inb[(kl + 1) * D_ + n];
        const int chunk = (kl >> 3) * 64 + n;
        const int e = kl & 7;
        *reinterpret_cast<unsigned*>(wsb + chunk * 16 + e * 2) =
            bf16_rne(x0) | (bf16_rne(x1) << 16);
    }

    // ---- thresh part: this wave's row
    const int row = blk * 4 + w;          // 0..8191
    const int b = row >> 11;
    const int rl = row & 2047;
    const float2* meshg = reinterpret_cast<const float2*>(mesh) + (size_t)b * L_;
    unsigned* hw = s_hist[w];
    float* cw = s_cand[w];
    const float2 me = meshg[rl];

    *reinterpret_cast<uint4*>(&hw[l * 4]) = make_uint4(0u, 0u, 0u, 0u);
    LDS_FENCE();
    #pragma unroll 4
    for (int it = 0; it < 32; ++it) {
        const int j = (it << 6) + l;
        const float2 mj = meshg[j];
        const float dx = __fsub_rn(me.x, mj.x);
        const float dy = __fsub_rn(me.y, mj.y);
        const float d = __fadd_rn(__fmul_rn(dx, dx), __fmul_rn(dy, dy));
        int bin = (int)(d * 128.0f); bin = bin < 255 ? bin : 255;
        atomicAdd(&hw[bin], 1u);
    }
    LDS_FENCE();
    // level-1 scan + crossings at ranks 409/410
    int lo, hi; unsigned base;
    {
        const uint4 hv = *reinterpret_cast<const uint4*>(&hw[l * 4]);
        const unsigned p0 = hv.x, p1 = p0 + hv.y, p2 = p1 + hv.z, p3 = p2 + hv.w;
        unsigned sc = p3;
        #pragma unroll
        for (int off = 1; off < 64; off <<= 1) {
            const unsigned uu = __shfl_up(sc, off);
            if (l >= off) sc += uu;
        }
        const unsigned eb = sc - p3;
        const unsigned cum[4] = {eb + p0, eb + p1, eb + p2, eb + p3};
        int flo = -1, fhi = -1; unsigned fbase = 0u;
        #pragma unroll
        for (int e = 0; e < 4; ++e) {
            const unsigned prev = e ? cum[e - 1] : eb;
            if (cum[e] > 409u && prev <= 409u) { flo = l * 4 + e; fbase = prev; }
            if (cum[e] > 410u && prev <= 410u) { fhi = l * 4 + e; }
        }
        const unsigned long long bmlo = __ballot(flo >= 0);
        const int srclo = (int)__builtin_ctzll(bmlo);
        lo = __shfl(flo, srclo);
        base = __shfl(fbase, srclo);
        const unsigned long long bmhi = __ballot(fhi >= 0);
        hi = __shfl(fhi, (int)__builtin_ctzll(bmhi));
    }
    // gather candidates from bins [lo,hi] — ballot compaction (no atomics)
    unsigned cbase = 0u;
    #pragma unroll 4
    for (int it = 0; it < 32; ++it) {
        const int j = (it << 6) + l;
        const float2 mj = meshg[j];
        const float dx = __fsub_rn(me.x, mj.x);
        const float dy = __fsub_rn(me.y, mj.y);
        const float d = __fadd_rn(__fmul_rn(dx, dx), __fmul_rn(dy, dy));
        int bin = (int)(d * 128.0f); bin = bin < 255 ? bin : 255;
        const bool pred = (bin >= lo && bin <= hi);
        const unsigned long long bm = __ballot(pred);
        if (pred) {
            const unsigned p = cbase + (unsigned)__popcll(bm & ((1ull << l) - 1ull));
            if (p < (unsigned)CAPC) cw[p] = d;
        }
        cbase += (unsigned)__popcll(bm);
    }
    LDS_FENCE();
    const int m = (int)min(cbase, (unsigned)CAPC);
    const unsigned k409 = 409u - base;      // rank within cw
    const unsigned k410 = 410u - base;
    // ---- level-2 refine: 256 sub-bins over candidate range
    const float lo_edge = (float)lo * 0.0078125f;          // lo/128, exact
    const float sc2 = 32768.0f / (float)(hi - lo + 1);     // 256*128/(span bins)
    *reinterpret_cast<uint4*>(&hw[l * 4]) = make_uint4(0u, 0u, 0u, 0u);
    LDS_FENCE();
    #pragma unroll 2
    for (int ci = l; ci < m; ci += 64) {
        const float v = cw[ci];
        int b2 = (int)(__fmul_rn(__fsub_rn(v, lo_edge), sc2));
        b2 = b2 < 255 ? b2 : 255; b2 = b2 > 0 ? b2 : 0;
        atomicAdd(&hw[b2], 1u);
    }
    LDS_FENCE();
    int lo2, hi2; unsigned base2;
    {
        const uint4 hv = *reinterpret_cast<const uint4*>(&hw[l * 4]);
        const unsigned p0 = hv.x, p1 = p0 + hv.y, p2 = p1 + hv.z, p3 = p2 + hv.w;
        unsigned sc = p3;
        #pragma unroll
        for (int off = 1; off < 64; off <<= 1) {
            const unsigned uu = __shfl_up(sc, off);
            if (l >= off) sc += uu;
        }
        const unsigned eb = sc - p3;
        const unsigned cum[4] = {eb + p0, eb + p1, eb + p2, eb + p3};
        int flo = -1, fhi = -1; unsigned fbase = 0u;
        #pragma unroll
        for (int e = 0; e < 4; ++e) {
            const unsigned prev = e ? cum[e - 1] : eb;
            if (cum[e] > k409 && prev <= k409) { flo = l * 4 + e; fbase = prev; }
            if (cum[e] > k410 && prev <= k410) { fhi = l * 4 + e; }
        }
        const unsigned long long bmlo = __ballot(flo >= 0);
        const int srclo = (int)__builtin_ctzll(bmlo);
        lo2 = __shfl(flo, srclo);
        base2 = __shfl(fbase, srclo);
        const unsigned long long bmhi = __ballot(fhi >= 0);
        hi2 = __shfl(fhi, (int)__builtin_ctzll(bmhi));
    }
    // gather2 into c2 (dead hist region) — ballot compaction
    float* c2 = reinterpret_cast<float*>(hw);
    unsigned cnt2 = 0u;
    for (int c0 = 0; c0 < m; c0 += 64) {
        const int ci = c0 + l;
        float v = 0.0f; bool pred = false;
        if (ci < m) {
            v = cw[ci];
            int b2 = (int)(__fmul_rn(__fsub_rn(v, lo_edge), sc2));
            b2 = b2 < 255 ? b2 : 255; b2 = b2 > 0 ? b2 : 0;
            pred = (b2 >= lo2 && b2 <= hi2);
        }
        const unsigned long long bm = __ballot(pred);
        if (pred) {
            const unsigned p = cnt2 + (unsigned)__popcll(bm & ((1ull << l) - 1ull));
            if (p < 256u) c2[p] = v;
        }
        cnt2 += (unsigned)__popcll(bm);
    }
    LDS_FENCE();
    const int c = (int)min(cnt2, 256u);
    const int q409 = (int)(k409 - base2);
    const int q410 = (int)(k410 - base2);
    // result slots (cand region is dead now); deterministic 0 fallback
    if (l == 0) { cw[0] = 0.0f; cw[1] = 0.0f; }
    LDS_FENCE();
    #pragma unroll 1
    for (int cc0 = 0; cc0 < c; cc0 += 64) {
        const int ci = cc0 + l;
        const float v = (ci < c) ? c2[ci] : 0.0f;
        int lt = 0, le = 0;
        #pragma unroll 4
        for (int i = 0; i < c; ++i) {
            const float u = c2[i];
            lt += (u < v) ? 1 : 0;
            le += (u <= v) ? 1 : 0;
        }
        if (ci < c) {
            if (lt <= q409 && q409 < le) cw[0] = v;
            if (lt <= q410 && q410 < le) cw[1] = v;
        }
    }
    LDS_FENCE();
    if (l == 0) {
        // threshold in d-space (head-independent): thD strictly inside the
        // (d409,d410) order-stat gap => {d<=thD} == {d*s <= lerp(d409*s,d410*s)}
        const float d409 = cw[0], d410 = cw[1];
        const float pos = 0.2f * 2047.0f;
        const float g = pos - 409.0f;
        const float lw = 1.0f - g;
        const float thD = __fadd_rn(__fmul_rn(d409, lw), __fmul_rn(d410, g));
        out[(size_t)(b * L_ + rl) * OUTW + 319] = thD;   // scratch, posatt overwrites
    }
}

// ---- posatt v5b: A M-dim = 16 mesh rows, plane = head (4 planes).
// Distances computed ONCE per (row,k); one 8-fragment B tile feeds 32 MFMAs.
// 4 waves, each owns disjoint K-tiles (w, w+4, ..., w+28); no barriers in loop.
// Mesh staged in LDS (time-shared with epilogue C buffer).
// v5b fix: B sub-k-step stride is s*4096 (4 kchunks * 64 chunks * 16 B), the
// R5 s*16384 read past the tile (garbage bf16 -> NaN).
__global__ __launch_bounds__(256, 2) void posatt_kernel(
    const float* __restrict__ mesh,     // (B,L,2)
    const float* __restrict__ inputs,   // (B,L,D)
    const float* __restrict__ lmda,     // (H)
    const char* __restrict__ ws,        // bf16 chunk-major inputs
    float* __restrict__ out)            // (B,L,320); col 319 holds thD scratch
{
    __shared__ __align__(16) char s_mem[16384];  // mesh (main) | C[64][64] (epi)
    __shared__ float s_scale[H_];
    __shared__ float s_thD[RB];
    __shared__ float s_wsumW[4][H_][RB];         // per-wave partial wsums

    const int t = threadIdx.x;          // 256 threads
    const int l = t & 63;
    const int w = t >> 6;               // 0..3

    // swizzle: both co-resident blocks per CU (ids 256 apart) share one batch
    const int blk = blockIdx.x;         // 512
    const int b = (blk >> 6) & 3;
    const int rbk = ((blk >> 8) << 6) | (blk & 63);   // 0..127
    const int n0 = rbk * RB;

    const float2* meshg = reinterpret_cast<const float2*>(mesh) + (size_t)b * L_;

    // per-head scale (exact, verified R2 path)
    if (t < H_) {
        const double lam = (double)lmda[t];
        const float C = (float)(0.25 * M_PI * (1.0 - 1e-07));
        const float s1 = (float)sin(lam);
        const float arg = __fmul_rn(C, __fadd_rn(1.0f, s1));
        s_scale[t] = (float)tan((double)arg);
    }
    // per-row thresholds from scratch slots (own rows only; read precedes write)
    if (t < RB) {
        s_thD[t] = out[(size_t)(b * L_ + n0 + t) * OUTW + 319];
    }
    // stage mesh (16 KB) into LDS
    {
        const float4* mg4 = reinterpret_cast<const float4*>(meshg);
        float4* sm4 = reinterpret_cast<float4*>(s_mem);
        #pragma unroll
        for (int i = 0; i < 4; ++i) sm4[t + i * 256] = mg4[t + i * 256];
    }
    __syncthreads();

    const int rr = l & 15;              // mesh row within block (= A M-row)
    const int kq = l >> 4;              // k-quad 0..3
    const float2 me = meshg[n0 + rr];
    const float thD = s_thD[rr];
    constexpr float LOG2E = 1.4426950408889634f;
    float cH[H_];
    #pragma unroll
    for (int h = 0; h < H_; ++h) cH[h] = __fmul_rn(-LOG2E, s_scale[h]);

    // B lane base: chunk = (tl*8 + s*4 + kq)*64 + nq*16 + rr
    const char* blane = ws + (size_t)b * (L_ * D_ * 2) + ((kq * 64 + rr) << 4);
    const float4* smesh4 = reinterpret_cast<const float4*>(s_mem) + (kq << 2);

    f32x4 acc[H_][4];                   // [head][nq]
    #pragma unroll
    for (int h = 0; h < H_; ++h)
        #pragma unroll
        for (int nq = 0; nq < 4; ++nq) acc[h][nq] = (f32x4)0.0f;
    float wacc[H_] = {0.f, 0.f, 0.f, 0.f};

    auto LOADB = [&](int tl, uint4 (&Bv)[8]) {
        const char* p = blane + (size_t)tl * 8192;
        #pragma unroll
        for (int s = 0; s < 2; ++s)
            #pragma unroll
            for (int nq = 0; nq < 4; ++nq)
                Bv[s * 4 + nq] = *reinterpret_cast<const uint4*>(
                    p + s * 4096 + nq * 256);
    };
    auto DIST = [&](float mx, float my) -> float {
        const float dx = __fsub_rn(me.x, mx);
        const float dy = __fsub_rn(me.y, my);
        return __fadd_rn(__fmul_rn(dx, dx), __fmul_rn(dy, dy));
    };
    auto COMPUTE = [&](int tl, const uint4 (&Bv)[8]) {
        #pragma unroll
        for (int s = 0; s < 2; ++s) {
            const float4* mq = smesh4 + (tl * 32 + s * 16);
            const float4 m0 = mq[0], m1 = mq[1], m2 = mq[2], m3 = mq[3];
            float d[8];
            d[0] = DIST(m0.x, m0.y); d[1] = DIST(m0.z, m0.w);
            d[2] = DIST(m1.x, m1.y); d[3] = DIST(m1.z, m1.w);
            d[4] = DIST(m2.x, m2.y); d[5] = DIST(m2.z, m2.w);
            d[6] = DIST(m3.x, m3.y); d[7] = DIST(m3.z, m3.w);
            #pragma unroll
            for (int h = 0; h < H_; ++h) {
                float wv[8];
                #pragma unroll
                for (int e = 0; e < 8; ++e) {
                    const float x = __fmul_rn(d[e], cH[h]);
                    wv[e] = (d[e] <= thD) ? EXP2F(x) : 0.0f;
                }
                wacc[h] = __fadd_rn(wacc[h],
                    __fadd_rn(__fadd_rn(__fadd_rn(wv[0], wv[1]),
                                        __fadd_rn(wv[2], wv[3])),
                              __fadd_rn(__fadd_rn(wv[4], wv[5]),
                                        __fadd_rn(wv[6], wv[7]))));
                union { uint4 u; bf16x8 v; } av;
                av.u = make_uint4(cvt_pk_bf16(wv[0], wv[1]),
                                  cvt_pk_bf16(wv[2], wv[3]),
                                  cvt_pk_bf16(wv[4], wv[5]),
                                  cvt_pk_bf16(wv[6], wv[7]));
                #pragma unroll
                for (int nq = 0; nq < 4; ++nq) {
                    union { uint4 u; bf16x8 v; } bv;
                    bv.u = Bv[s * 4 + nq];
                    acc[h][nq] = __builtin_amdgcn_mfma_f32_16x16x32_bf16(
                        av.v, bv.v, acc[h][nq], 0, 0, 0);
                }
            }
        }
    };

    // ping-pong over this wave's 8 tiles: w, w+4, ..., w+28
    uint4 bufA[8], bufB[8];
    LOADB(w, bufA);
    #pragma unroll 1
    for (int i = 0; i < 3; ++i) {
        LOADB(w + 4 * (2 * i + 1), bufB);
        COMPUTE(w + 4 * (2 * i), bufA);
        LOADB(w + 4 * (2 * i + 2), bufA);
        COMPUTE(w + 4 * (2 * i + 1), bufB);
    }
    LOADB(w + 28, bufB);
    COMPUTE(w + 24, bufA);
    COMPUTE(w + 28, bufB);

    // per-wave wsum partials: reduce over kq lane groups (xor 16, 32)
    #pragma unroll
    for (int h = 0; h < H_; ++h) {
        wacc[h] += __shfl_xor(wacc[h], 16);
        wacc[h] += __shfl_xor(wacc[h], 32);
    }
    if (l < RB) {
        #pragma unroll
        for (int h = 0; h < H_; ++h) s_wsumW[w][h][l] = wacc[h];
    }

    __syncthreads();                    // all waves done with s_mesh
    // zero C region (16 KB)
    {
        float4* Cz = reinterpret_cast<float4*>(s_mem);
        #pragma unroll
        for (int i = 0; i < 4; ++i)
            Cz[t + i * 256] = make_float4(0.f, 0.f, 0.f, 0.f);
    }
    __syncthreads();
    // reduce per-wave K-partials into C[64][64] (row = h*16 + mrow)
    {
        float* Cf = reinterpret_cast<float*>(s_mem);
        #pragma unroll
        for (int h = 0; h < H_; ++h)
            #pragma unroll
            for (int nq = 0; nq < 4; ++nq)
                #pragma unroll
                for (int reg = 0; reg < 4; ++reg) {
                    const int mrow = kq * 4 + reg;
                    const int col = nq * 16 + rr;
                    atomicAdd(&Cf[(h * 16 + mrow) * 64 + col], acc[h][nq][reg]);
                }
    }
    __syncthreads();
    // normalize + store conv block
    {
        const float* Cf = reinterpret_cast<const float*>(s_mem);
        #pragma unroll
        for (int q = 0; q < 4; ++q) {
            const int s = t + q * 256;          // 0..1023
            const int pr = s >> 4;              // 0..63 = h*16 + mrow
            const int h = pr >> 4;
            const int mrow = pr & 15;
            const int col = (s & 15) << 2;
            const float wsv = ((s_wsumW[0][h][mrow] + s_wsumW[1][h][mrow]) +
                               (s_wsumW[2][h][mrow] + s_wsumW[3][h][mrow]));
            const float inv = (wsv != 0.0f) ? 1.0f / wsv : 0.0f;
            float4 r0 = *reinterpret_cast<const float4*>(&Cf[pr * 64 + col]);
            r0.x *= inv; r0.y *= inv; r0.z *= inv; r0.w *= inv;
            float* op = out + (size_t)(b * L_ + n0 + mrow) * OUTW + D_ + h * 64 + col;
            *reinterpret_cast<float4*>(op) = r0;
        }
    }
    // exact fp32 passthrough of inputs into out[:, :, 0:64]
    {
        const float* inpb = inputs + (size_t)b * L_ * D_;
        const int r = t >> 4;                   // 0..15
        const int c = (t & 15) << 2;
        const float4 v = *reinterpret_cast<const float4*>(
            &inpb[(size_t)(n0 + r) * D_ + c]);
        *reinterpret_cast<float4*>(
            &out[(size_t)(b * L_ + n0 + r) * OUTW + c]) = v;
    }
}

extern "C" void kernel_launch(void* const* d_in, const int* in_sizes, int n_in,
                              void* d_out, int out_size, void* d_ws, size_t ws_size,
                              hipStream_t stream) {
    const float* mesh   = (const float*)d_in[0];
    const float* inputs = (const float*)d_in[1];
    const float* lmda   = (const float*)d_in[2];
    float* out = (float*)d_out;
    char* ws = (char*)d_ws;
    (void)in_sizes; (void)n_in; (void)out_size; (void)ws_size;
    hipLaunchKernelGGL(prep_thresh_kernel, dim3(2048), dim3(256), 0, stream,
                       mesh, inputs, ws, out);
    hipLaunchKernelGGL(posatt_kernel, dim3(B_ * (L_ / RB)), dim3(256), 0, stream,
                       mesh, inputs, lmda, ws, out);
}